// Round 1
// baseline (389.790 us; speedup 1.0000x reference)
//
#include <hip/hip_runtime.h>
#include <hip/hip_bf16.h>
#include <cstdint>

typedef __bf16 bf16;
typedef __bf16 bf16x8 __attribute__((ext_vector_type(8)));
typedef __bf16 bf16x4 __attribute__((ext_vector_type(4)));
typedef float floatx4 __attribute__((ext_vector_type(4)));

#define MFMA16(a, b, c) __builtin_amdgcn_mfma_f32_16x16x32_bf16(a, b, c, 0, 0, 0)

__device__ __forceinline__ void gload_lds16(const void* g, void* l) {
    __builtin_amdgcn_global_load_lds(
        (const __attribute__((address_space(1))) void*)g,
        (__attribute__((address_space(3))) void*)l, 16, 0, 0);
}

// Raw barrier: no vmcnt(0)/lgkmcnt(0) drain (unlike __syncthreads), but a
// compile-time memory fence so LDS reads / global_load_lds can't cross it.
#define BARRIER()    asm volatile("s_barrier" ::: "memory")
#define WAIT_LGKM0() asm volatile("s_waitcnt lgkmcnt(0)" ::: "memory")

// ---------------------------------------------------------------------------
// fp32 -> bf16 flat downcast
// ---------------------------------------------------------------------------
__global__ void downcast_kernel(const float* __restrict__ in, bf16* __restrict__ out,
                                size_t n) {
    const size_t i = ((size_t)blockIdx.x * blockDim.x + threadIdx.x) * 4;
    if (i >= n) return;
    const float4 v = *(const float4*)(in + i);
    bf16x4 o = {(bf16)v.x, (bf16)v.y, (bf16)v.z, (bf16)v.w};
    *(bf16x4*)(out + i) = o;
}

// ---------------------------------------------------------------------------
// Transpose + downcast: in fp32 [R][C] -> out bf16 [C][R]
// ---------------------------------------------------------------------------
__global__ void transpose_kernel(const float* __restrict__ in, bf16* __restrict__ out,
                                 int R, int C) {
    __shared__ float tile[32][33];
    const int c0 = blockIdx.x * 32, r0 = blockIdx.y * 32;
    const int tx = threadIdx.x & 31, ty = threadIdx.x >> 5;
    for (int i = 0; i < 32; i += 8)
        tile[ty + i][tx] = in[(size_t)(r0 + ty + i) * C + (c0 + tx)];
    __syncthreads();
    for (int i = 0; i < 32; i += 8)
        out[(size_t)(c0 + ty + i) * R + (r0 + tx)] = (bf16)tile[tx][ty + i];
}

// ---------------------------------------------------------------------------
// 8-phase 256x256 GEMM for the qkv projection (MODE-0 replacement).
// C[M][N] = A[M][K] @ BT[N][K]^T, bf16 in, fp32 accum, epilogue scatters
// to q/k/v (N = 6144 = [3][16][128]).
//
// Geometry: BM=BN=256, BK=64, 512 threads = 8 waves (2M x 4N), per-wave
// C = 128x64 -> acc[8][4]. LDS 128 KiB = double-buffered A+B K-tiles.
// Swizzle: identical 16B-segment XOR as the verified 128^2 kernel
// (LDS position (row,sp) holds global segment sp ^ (row&7)).
//
// Schedule per K-tile t (buffer b = t&1), 4 phases:
//   ph0: ds_read a[0..3][kc], b[0..1][kc]; stage B(t+1,h0)->buf b^1
//   ph1: ds_read b[2..3][kc];              stage B(t+1,h1)->buf b^1
//   ph2: ds_read a[4..7][kc]
//   ph3: (all frags reused from regs);     stage A(t+2,h0+h1)->buf b
// Each phase: BARRIER; lgkmcnt(0); setprio(1); 16 MFMA; setprio(0); BARRIER.
// vmcnt(4) ONCE per tile (end of ph3) -> A(t+2)'s 4 loads stay in flight
// across the barrier (T4 counted-vmcnt; never drain to 0 in the loop).
// WAR safety: A-halves of buf b last LDS-read in ph2 (barrier-separated
// from ph3's stage issue); B(t+1) goes to the non-read buffer.
// ---------------------------------------------------------------------------
__global__ __launch_bounds__(512) void gemm256_qkv_kernel(
    const bf16* __restrict__ A, const bf16* __restrict__ BT, int K,
    bf16* __restrict__ qt, bf16* __restrict__ kt, bf16* __restrict__ vt) {
    __shared__ alignas(16) bf16 As[2][16384];  // 64 KB
    __shared__ alignas(16) bf16 Bs[2][16384];  // 64 KB

    const int tid = threadIdx.x;
    const int wave = tid >> 6, lane = tid & 63;
    const int quad = lane >> 4, r16 = lane & 15;

    // bijective XCD swizzle over the 24x16 grid (384 blocks, 48 per XCD)
    const int flat = blockIdx.y * 24 + blockIdx.x;
    const int swz = (flat & 7) * 48 + (flat >> 3);
    const int n0 = (swz % 24) << 8, m0 = (swz / 24) << 8;

    const int wm = (wave >> 2) << 7;  // 0 or 128
    const int wn = (wave & 3) << 6;   // 0,64,128,192

    // staging map: per half-tile (128 rows x 64 cols) each thread does 2
    // 16B chunks; chunk c: row=c>>3, sp=c&7, global segment s = sp^(row&7)
    int srow[2], soff[2];
#pragma unroll
    for (int j = 0; j < 2; ++j) {
        const int c = tid + j * 512;
        srow[j] = c >> 3;
        soff[j] = ((c & 7) ^ (srow[j] & 7)) * 8;
    }

    const int NT = K >> 6;  // 32 K-tiles

    auto stageA = [&](int bufi, int hf, int kt_) {
#pragma unroll
        for (int j = 0; j < 2; ++j) {
            const int c = tid + j * 512;
            gload_lds16(A + (size_t)(m0 + hf * 128 + srow[j]) * K + (kt_ << 6) + soff[j],
                        &As[bufi][hf * 8192 + c * 8]);
        }
    };
    auto stageB = [&](int bufi, int hf, int kt_) {
#pragma unroll
        for (int j = 0; j < 2; ++j) {
            const int c = tid + j * 512;
            gload_lds16(BT + (size_t)(n0 + hf * 128 + srow[j]) * K + (kt_ << 6) + soff[j],
                        &Bs[bufi][hf * 8192 + c * 8]);
        }
    };

    floatx4 acc[8][4] = {};

    // prologue: tile0 A+B -> buf0, tile1 A -> buf1. vmcnt(4) = tile0 landed,
    // tile1's A (4 loads) still in flight.
    stageA(0, 0, 0); stageA(0, 1, 0);
    stageB(0, 0, 0); stageB(0, 1, 0);
    stageA(1, 0, 1); stageA(1, 1, 1);
    asm volatile("s_waitcnt vmcnt(4)" ::: "memory");
    BARRIER();

    for (int t = 0; t < NT; ++t) {
        const int bsel = t & 1;
        const bf16* Ab = &As[bsel][0];
        const bf16* Bb = &Bs[bsel][0];
        bf16x8 alo[4][2], ahi[4][2], blo[2][2], bhi[2][2];

        // ---- phase 0: quadrant (i0-3 x j0-1) -------------------------------
#pragma unroll
        for (int i = 0; i < 4; ++i) {
            const int row = wm + i * 16 + r16;
#pragma unroll
            for (int kc = 0; kc < 2; ++kc)
                alo[i][kc] = *(const bf16x8*)(Ab + row * 64 + ((4 * kc + quad) ^ (row & 7)) * 8);
        }
#pragma unroll
        for (int j = 0; j < 2; ++j) {
            const int row = wn + j * 16 + r16;
#pragma unroll
            for (int kc = 0; kc < 2; ++kc)
                blo[j][kc] = *(const bf16x8*)(Bb + row * 64 + ((4 * kc + quad) ^ (row & 7)) * 8);
        }
        if (t + 1 < NT) stageB(bsel ^ 1, 0, t + 1);
        BARRIER();
        WAIT_LGKM0();
        __builtin_amdgcn_s_setprio(1);
#pragma unroll
        for (int i = 0; i < 4; ++i)
#pragma unroll
            for (int j = 0; j < 2; ++j)
#pragma unroll
                for (int kc = 0; kc < 2; ++kc)
                    acc[i][j] = MFMA16(alo[i][kc], blo[j][kc], acc[i][j]);
        __builtin_amdgcn_s_setprio(0);
        BARRIER();

        // ---- phase 1: quadrant (i0-3 x j2-3) -------------------------------
#pragma unroll
        for (int j = 0; j < 2; ++j) {
            const int row = wn + (2 + j) * 16 + r16;
#pragma unroll
            for (int kc = 0; kc < 2; ++kc)
                bhi[j][kc] = *(const bf16x8*)(Bb + row * 64 + ((4 * kc + quad) ^ (row & 7)) * 8);
        }
        if (t + 1 < NT) stageB(bsel ^ 1, 1, t + 1);
        BARRIER();
        WAIT_LGKM0();
        __builtin_amdgcn_s_setprio(1);
#pragma unroll
        for (int i = 0; i < 4; ++i)
#pragma unroll
            for (int j = 0; j < 2; ++j)
#pragma unroll
                for (int kc = 0; kc < 2; ++kc)
                    acc[i][2 + j] = MFMA16(alo[i][kc], bhi[j][kc], acc[i][2 + j]);
        __builtin_amdgcn_s_setprio(0);
        BARRIER();

        // ---- phase 2: quadrant (i4-7 x j2-3) -------------------------------
#pragma unroll
        for (int i = 0; i < 4; ++i) {
            const int row = wm + (4 + i) * 16 + r16;
#pragma unroll
            for (int kc = 0; kc < 2; ++kc)
                ahi[i][kc] = *(const bf16x8*)(Ab + row * 64 + ((4 * kc + quad) ^ (row & 7)) * 8);
        }
        BARRIER();
        WAIT_LGKM0();
        __builtin_amdgcn_s_setprio(1);
#pragma unroll
        for (int i = 0; i < 4; ++i)
#pragma unroll
            for (int j = 0; j < 2; ++j)
#pragma unroll
                for (int kc = 0; kc < 2; ++kc)
                    acc[4 + i][2 + j] = MFMA16(ahi[i][kc], bhi[j][kc], acc[4 + i][2 + j]);
        __builtin_amdgcn_s_setprio(0);
        BARRIER();

        // ---- phase 3: quadrant (i4-7 x j0-1), frags from regs --------------
        if (t + 2 < NT) { stageA(bsel, 0, t + 2); stageA(bsel, 1, t + 2); }
        BARRIER();
        __builtin_amdgcn_s_setprio(1);
#pragma unroll
        for (int i = 0; i < 4; ++i)
#pragma unroll
            for (int j = 0; j < 2; ++j)
#pragma unroll
                for (int kc = 0; kc < 2; ++kc)
                    acc[4 + i][j] = MFMA16(ahi[i][kc], blo[j][kc], acc[4 + i][j]);
        __builtin_amdgcn_s_setprio(0);
        if (t + 2 < NT) asm volatile("s_waitcnt vmcnt(4)" ::: "memory");
        else            asm volatile("s_waitcnt vmcnt(0)" ::: "memory");
        BARRIER();
    }

    // ---- epilogue: scatter to q/k/v (same mapping as verified kernel) ------
    const int tsel = n0 >> 11;  // block-uniform: which of q/k/v
    const float qscale = 0.08838834764831845f;  // 128^-0.5
#pragma unroll
    for (int i = 0; i < 8; ++i) {
        const int mbase = m0 + wm + i * 16 + quad * 4;
        const int b_ = mbase >> 11;
        const int s = mbase & 2047;
#pragma unroll
        for (int j = 0; j < 4; ++j) {
            const int n = n0 + wn + j * 16 + r16;
            const int h = (n >> 7) & 15, hd = n & 127;
            const int bh = b_ * 16 + h;
            if (tsel == 0) {
#pragma unroll
                for (int r = 0; r < 4; ++r)
                    qt[(size_t)(bh * 2048 + s + r) * 128 + hd] =
                        (bf16)(acc[i][j][r] * qscale);
            } else if (tsel == 1) {
#pragma unroll
                for (int r = 0; r < 4; ++r)
                    kt[(size_t)(bh * 2048 + s + r) * 128 + hd] = (bf16)acc[i][j][r];
            } else {
                bf16x4 pv = {(bf16)acc[i][j][0], (bf16)acc[i][j][1],
                             (bf16)acc[i][j][2], (bf16)acc[i][j][3]};
                *(bf16x4*)(vt + (size_t)(bh * 128 + hd) * 2048 + s) = pv;
            }
        }
    }
}

// ---------------------------------------------------------------------------
// GEMM: C[M][N] = A[M][K] @ BT[N][K]^T   (bf16 in, fp32 accum)
// 128^2 m97-structure; kept for the Wo projection (MODE 1): its grid is
// 512 blocks (2/CU) where the 256^2 template would quantize to 0.5 blocks/CU.
// ---------------------------------------------------------------------------
template <int MODE>
__global__ __launch_bounds__(256) void gemm_bt_kernel(
    const bf16* __restrict__ A, const bf16* __restrict__ BT,
    int M, int N, int K,
    bf16* __restrict__ qt, bf16* __restrict__ kt, bf16* __restrict__ vt,
    float* __restrict__ Cout) {
    __shared__ alignas(16) bf16 As[128 * 64];  // 16 KB
    __shared__ alignas(16) bf16 Bs[128 * 64];  // 16 KB

    const int tid = threadIdx.x;
    const int wave = tid >> 6, lane = tid & 63;
    const int quad = lane >> 4, r16 = lane & 15;
    const int m0 = blockIdx.y * 128, n0 = blockIdx.x * 128;
    const int wm = (wave >> 1) * 64, wn = (wave & 1) * 64;

    int srow[4], soff[4];
#pragma unroll
    for (int j = 0; j < 4; ++j) {
        const int c = tid + j * 256;
        srow[j] = c >> 3;
        soff[j] = ((c & 7) ^ (srow[j] & 7)) * 8;
    }

    floatx4 acc[4][4] = {};

    for (int k0 = 0; k0 < K; k0 += 64) {
        __syncthreads();
#pragma unroll
        for (int j = 0; j < 4; ++j) {
            const int c = tid + j * 256;
            gload_lds16(A + (size_t)(m0 + srow[j]) * K + k0 + soff[j], As + c * 8);
            gload_lds16(BT + (size_t)(n0 + srow[j]) * K + k0 + soff[j], Bs + c * 8);
        }
        __syncthreads();

#pragma unroll
        for (int kc = 0; kc < 2; ++kc) {
            bf16x8 a[4], b[4];
#pragma unroll
            for (int i = 0; i < 4; ++i) {
                const int row = wm + i * 16 + r16;
                const int sp = (4 * kc + quad) ^ (row & 7);
                a[i] = *(const bf16x8*)(As + row * 64 + sp * 8);
            }
#pragma unroll
            for (int j = 0; j < 4; ++j) {
                const int row = wn + j * 16 + r16;
                const int sp = (4 * kc + quad) ^ (row & 7);
                b[j] = *(const bf16x8*)(Bs + row * 64 + sp * 8);
            }
#pragma unroll
            for (int i = 0; i < 4; ++i)
#pragma unroll
                for (int j = 0; j < 4; ++j)
                    acc[i][j] = MFMA16(a[i], b[j], acc[i][j]);
        }
    }

    if (MODE == 0) {
        const int t = n0 >> 11;
        const float qscale = 0.08838834764831845f;
#pragma unroll
        for (int i = 0; i < 4; ++i) {
            const int mbase = m0 + wm + i * 16 + quad * 4;
            const int b_ = mbase >> 11;
            const int s = mbase & 2047;
#pragma unroll
            for (int j = 0; j < 4; ++j) {
                const int n = n0 + wn + j * 16 + r16;
                const int h = (n >> 7) & 15, hd = n & 127;
                const int bh = b_ * 16 + h;
                if (t == 0) {
#pragma unroll
                    for (int r = 0; r < 4; ++r)
                        qt[(size_t)(bh * 2048 + s + r) * 128 + hd] =
                            (bf16)(acc[i][j][r] * qscale);
                } else if (t == 1) {
#pragma unroll
                    for (int r = 0; r < 4; ++r)
                        kt[(size_t)(bh * 2048 + s + r) * 128 + hd] = (bf16)acc[i][j][r];
                } else {
                    bf16x4 pv = {(bf16)acc[i][j][0], (bf16)acc[i][j][1],
                                 (bf16)acc[i][j][2], (bf16)acc[i][j][3]};
                    *(bf16x4*)(vt + (size_t)(bh * 128 + hd) * 2048 + s) = pv;
                }
            }
        }
    } else {
#pragma unroll
        for (int i = 0; i < 4; ++i) {
            const int mbase = m0 + wm + i * 16 + quad * 4;
#pragma unroll
            for (int j = 0; j < 4; ++j) {
                const int n = n0 + wn + j * 16 + r16;
#pragma unroll
                for (int r = 0; r < 4; ++r)
                    Cout[(size_t)(mbase + r) * N + n] = acc[i][j][r];
            }
        }
    }
}

// ---------------------------------------------------------------------------
// Flash attention (causal), no-max softmax, work-paired. (unchanged)
// Grid: (16 pairs, 32 bh). Block p does q-tiles {p, 31-p} (64 rows each).
// 4 waves x 16 q-rows. BN=64. Diagonal-only masking.
// LDS K/V tiles XOR-swizzled at 16B segments; Ps row stride 72.
// ---------------------------------------------------------------------------
__global__ __launch_bounds__(256) void attn_kernel(
    const bf16* __restrict__ qt, const bf16* __restrict__ kt,
    const bf16* __restrict__ vt, bf16* __restrict__ o) {
    __shared__ alignas(16) bf16 Ks[64 * 128];    // (row, sp): seg = sp ^ (row&15)
    __shared__ alignas(16) bf16 Vts[128 * 64];   // (row, sp): seg = sp ^ (row&7)
    __shared__ alignas(16) bf16 Ps[4][16 * 72];  // per-wave P [row][key], stride 72

    const int tid = threadIdx.x;
    const int wave = tid >> 6, lane = tid & 63;
    const int quad = lane >> 4, r16 = lane & 15;
    const int pair = blockIdx.x, bh = blockIdx.y;
    const int b_ = bh >> 4, h = bh & 15;

    for (int half = 0; half < 2; ++half) {
        const int t = half == 0 ? pair : 31 - pair;
        const int q0 = t * 64;

        bf16x8 aq[4];
        {
            const bf16* qbase = qt + (((size_t)bh * 2048 + q0 + wave * 16 + r16) << 7);
#pragma unroll
            for (int kc = 0; kc < 4; ++kc)
                aq[kc] = *(const bf16x8*)(qbase + kc * 32 + quad * 8);
        }

        floatx4 oacc[8] = {};
        float lsum[4] = {0.f, 0.f, 0.f, 0.f};

        for (int it = 0; it <= t; ++it) {
            const int k0 = it * 64;
            __syncthreads();
#pragma unroll
            for (int j = 0; j < 4; ++j) {
                const int c = tid + j * 256;
                const int row = c >> 4, sp = c & 15, s = sp ^ (row & 15);
                gload_lds16(kt + (((size_t)bh * 2048 + k0 + row) << 7) + s * 8,
                            Ks + c * 8);
            }
#pragma unroll
            for (int j = 0; j < 4; ++j) {
                const int c = tid + j * 256;
                const int row = c >> 3, sp = c & 7, s = sp ^ (row & 7);
                gload_lds16(vt + ((size_t)bh * 128 + row) * 2048 + k0 + s * 8,
                            Vts + c * 8);
            }
            __syncthreads();

            floatx4 sacc[4] = {};
#pragma unroll
            for (int nt = 0; nt < 4; ++nt) {
                const int row = nt * 16 + r16;
#pragma unroll
                for (int kc = 0; kc < 4; ++kc) {
                    const int sp = (4 * kc + quad) ^ r16;
                    bf16x8 bk = *(const bf16x8*)(Ks + row * 128 + sp * 8);
                    sacc[nt] = MFMA16(aq[kc], bk, sacc[nt]);
                }
            }

            const int qrowC = q0 + wave * 16 + quad * 4;
            float p[4][4];
            if (it == t) {
#pragma unroll
                for (int nt = 0; nt < 4; ++nt)
#pragma unroll
                    for (int r = 0; r < 4; ++r) {
                        const bool ok = (k0 + nt * 16 + r16) <= (qrowC + r);
                        const float e = ok ? __expf(sacc[nt][r]) : 0.f;
                        p[nt][r] = e;
                        lsum[r] += e;
                    }
            } else {
#pragma unroll
                for (int nt = 0; nt < 4; ++nt)
#pragma unroll
                    for (int r = 0; r < 4; ++r) {
                        const float e = __expf(sacc[nt][r]);
                        p[nt][r] = e;
                        lsum[r] += e;
                    }
            }

#pragma unroll
            for (int nt = 0; nt < 4; ++nt)
#pragma unroll
                for (int r = 0; r < 4; ++r)
                    Ps[wave][(quad * 4 + r) * 72 + nt * 16 + r16] = (bf16)p[nt][r];

#pragma unroll
            for (int kblk = 0; kblk < 2; ++kblk) {
                bf16x8 ap = *(const bf16x8*)(&Ps[wave][r16 * 72 + kblk * 32 + quad * 8]);
#pragma unroll
                for (int nt2 = 0; nt2 < 8; ++nt2) {
                    const int row = nt2 * 16 + r16;
                    const int sp = (4 * kblk + quad) ^ (row & 7);
                    bf16x8 bv = *(const bf16x8*)(Vts + row * 64 + sp * 8);
                    oacc[nt2] = MFMA16(ap, bv, oacc[nt2]);
                }
            }
        }

#pragma unroll
        for (int r = 0; r < 4; ++r) {
            float s = lsum[r];
#pragma unroll
            for (int off = 1; off < 16; off <<= 1) s += __shfl_xor(s, off);
            lsum[r] = s;
        }

#pragma unroll
        for (int r = 0; r < 4; ++r) {
            const int qq = q0 + wave * 16 + quad * 4 + r;
            const float inv = 1.0f / lsum[r];
            bf16* orow = o + (size_t)(b_ * 2048 + qq) * 2048 + h * 128;
#pragma unroll
            for (int nt2 = 0; nt2 < 8; ++nt2)
                orow[nt2 * 16 + r16] = (bf16)(oacc[nt2][r] * inv);
        }
    }
}

// ---------------------------------------------------------------------------
extern "C" void kernel_launch(void* const* d_in, const int* in_sizes, int n_in,
                              void* d_out, int out_size, void* d_ws, size_t ws_size,
                              hipStream_t stream) {
    const float* x    = (const float*)d_in[0];  // [4096][2048] fp32
    const float* Wqkv = (const float*)d_in[1];  // [2048][6144] fp32
    const float* Wo   = (const float*)d_in[2];  // [2048][2048] fp32
    float* out        = (float*)d_out;          // [4096][2048] fp32

    char* ws = (char*)d_ws;
    bf16* xb    = (bf16*)ws; ws += (size_t)4096 * 2048 * 2;
    bf16* WqkvT = (bf16*)ws; ws += (size_t)6144 * 2048 * 2;
    bf16* WoT   = (bf16*)ws; ws += (size_t)2048 * 2048 * 2;
    bf16* qt    = (bf16*)ws; ws += (size_t)32 * 2048 * 128 * 2;
    bf16* kt    = (bf16*)ws; ws += (size_t)32 * 2048 * 128 * 2;
    bf16* vt    = (bf16*)ws; ws += (size_t)32 * 128 * 2048 * 2;
    bf16* ob    = (bf16*)ws; ws += (size_t)4096 * 2048 * 2;

    downcast_kernel<<<8192, 256, 0, stream>>>(x, xb, (size_t)4096 * 2048);
    transpose_kernel<<<dim3(192, 64), 256, 0, stream>>>(Wqkv, WqkvT, 2048, 6144);
    transpose_kernel<<<dim3(64, 64), 256, 0, stream>>>(Wo, WoT, 2048, 2048);

    gemm256_qkv_kernel<<<dim3(24, 16), 512, 0, stream>>>(
        xb, WqkvT, 2048, qt, kt, vt);

    attn_kernel<<<dim3(16, 32), 256, 0, stream>>>(qt, kt, vt, ob);

    gemm_bt_kernel<1><<<dim3(16, 32), 256, 0, stream>>>(
        ob, WoT, 4096, 2048, 2048, nullptr, nullptr, nullptr, out);
}

// Round 2
// 367.952 us; speedup vs baseline: 1.0594x; 1.0594x over previous
//
#include <hip/hip_runtime.h>
#include <hip/hip_bf16.h>
#include <cstdint>

typedef __bf16 bf16;
typedef __bf16 bf16x8 __attribute__((ext_vector_type(8)));
typedef __bf16 bf16x4 __attribute__((ext_vector_type(4)));
typedef float floatx4 __attribute__((ext_vector_type(4)));

#define MFMA16(a, b, c) __builtin_amdgcn_mfma_f32_16x16x32_bf16(a, b, c, 0, 0, 0)

__device__ __forceinline__ void gload_lds16(const void* g, void* l) {
    __builtin_amdgcn_global_load_lds(
        (const __attribute__((address_space(1))) void*)g,
        (__attribute__((address_space(3))) void*)l, 16, 0, 0);
}

// ---------------------------------------------------------------------------
// fp32 -> bf16 flat downcast
// ---------------------------------------------------------------------------
__global__ void downcast_kernel(const float* __restrict__ in, bf16* __restrict__ out,
                                size_t n) {
    const size_t i = ((size_t)blockIdx.x * blockDim.x + threadIdx.x) * 4;
    if (i >= n) return;
    const float4 v = *(const float4*)(in + i);
    bf16x4 o = {(bf16)v.x, (bf16)v.y, (bf16)v.z, (bf16)v.w};
    *(bf16x4*)(out + i) = o;
}

// ---------------------------------------------------------------------------
// Transpose + downcast: in fp32 [R][C] -> out bf16 [C][R]
// ---------------------------------------------------------------------------
__global__ void transpose_kernel(const float* __restrict__ in, bf16* __restrict__ out,
                                 int R, int C) {
    __shared__ float tile[32][33];
    const int c0 = blockIdx.x * 32, r0 = blockIdx.y * 32;
    const int tx = threadIdx.x & 31, ty = threadIdx.x >> 5;
    for (int i = 0; i < 32; i += 8)
        tile[ty + i][tx] = in[(size_t)(r0 + ty + i) * C + (c0 + tx)];
    __syncthreads();
    for (int i = 0; i < 32; i += 8)
        out[(size_t)(c0 + ty + i) * R + (r0 + tx)] = (bf16)tile[tx][ty + i];
}

// ---------------------------------------------------------------------------
// GEMM: C[M][N] = A[M][K] @ BT[N][K]^T   (bf16 in, fp32 accum)
// Verified 128x128 structure (119 us for qkv). R1's 256^2 8-phase port
// regressed (140 us, MfmaUtil 28, 1 block/CU + 25% tail) -> reverted.
// MODE 0: epilogue scatters to q/k/v (N = 6144 = [3][16][128])
// MODE 1: epilogue writes FP32 C row-major [M][N]
// ---------------------------------------------------------------------------
template <int MODE>
__global__ __launch_bounds__(256) void gemm_bt_kernel(
    const bf16* __restrict__ A, const bf16* __restrict__ BT,
    int M, int N, int K,
    bf16* __restrict__ qt, bf16* __restrict__ kt, bf16* __restrict__ vt,
    float* __restrict__ Cout) {
    __shared__ alignas(16) bf16 As[128 * 64];  // 16 KB
    __shared__ alignas(16) bf16 Bs[128 * 64];  // 16 KB

    const int tid = threadIdx.x;
    const int wave = tid >> 6, lane = tid & 63;
    const int quad = lane >> 4, r16 = lane & 15;
    const int m0 = blockIdx.y * 128, n0 = blockIdx.x * 128;
    const int wm = (wave >> 1) * 64, wn = (wave & 1) * 64;

    // staging map: 4 chunks per matrix per thread; chunk c: row=c>>3, sp=c&7,
    // global seg s = sp ^ (row&7)
    int srow[4], soff[4];
#pragma unroll
    for (int j = 0; j < 4; ++j) {
        const int c = tid + j * 256;
        srow[j] = c >> 3;
        soff[j] = ((c & 7) ^ (srow[j] & 7)) * 8;
    }

    floatx4 acc[4][4] = {};

    for (int k0 = 0; k0 < K; k0 += 64) {
        __syncthreads();
#pragma unroll
        for (int j = 0; j < 4; ++j) {
            const int c = tid + j * 256;
            gload_lds16(A + (size_t)(m0 + srow[j]) * K + k0 + soff[j], As + c * 8);
            gload_lds16(BT + (size_t)(n0 + srow[j]) * K + k0 + soff[j], Bs + c * 8);
        }
        __syncthreads();

#pragma unroll
        for (int kc = 0; kc < 2; ++kc) {
            bf16x8 a[4], b[4];
#pragma unroll
            for (int i = 0; i < 4; ++i) {
                const int row = wm + i * 16 + r16;
                const int sp = (4 * kc + quad) ^ (row & 7);
                a[i] = *(const bf16x8*)(As + row * 64 + sp * 8);
            }
#pragma unroll
            for (int j = 0; j < 4; ++j) {
                const int row = wn + j * 16 + r16;
                const int sp = (4 * kc + quad) ^ (row & 7);
                b[j] = *(const bf16x8*)(Bs + row * 64 + sp * 8);
            }
#pragma unroll
            for (int i = 0; i < 4; ++i)
#pragma unroll
                for (int j = 0; j < 4; ++j)
                    acc[i][j] = MFMA16(a[i], b[j], acc[i][j]);
        }
    }

    if (MODE == 0) {
        const int t = n0 >> 11;  // block-uniform: which of q/k/v
        const float qscale = 0.08838834764831845f;  // 128^-0.5
#pragma unroll
        for (int i = 0; i < 4; ++i) {
            const int mbase = m0 + wm + i * 16 + quad * 4;
            const int b_ = mbase >> 11;
            const int s = mbase & 2047;
#pragma unroll
            for (int j = 0; j < 4; ++j) {
                const int n = n0 + wn + j * 16 + r16;
                const int h = (n >> 7) & 15, hd = n & 127;
                const int bh = b_ * 16 + h;
                if (t == 0) {
#pragma unroll
                    for (int r = 0; r < 4; ++r)
                        qt[(size_t)(bh * 2048 + s + r) * 128 + hd] =
                            (bf16)(acc[i][j][r] * qscale);
                } else if (t == 1) {
#pragma unroll
                    for (int r = 0; r < 4; ++r)
                        kt[(size_t)(bh * 2048 + s + r) * 128 + hd] = (bf16)acc[i][j][r];
                } else {
                    bf16x4 pv = {(bf16)acc[i][j][0], (bf16)acc[i][j][1],
                                 (bf16)acc[i][j][2], (bf16)acc[i][j][3]};
                    *(bf16x4*)(vt + (size_t)(bh * 128 + hd) * 2048 + s) = pv;
                }
            }
        }
    } else {
#pragma unroll
        for (int i = 0; i < 4; ++i) {
            const int mbase = m0 + wm + i * 16 + quad * 4;
#pragma unroll
            for (int j = 0; j < 4; ++j) {
                const int n = n0 + wn + j * 16 + r16;
#pragma unroll
                for (int r = 0; r < 4; ++r)
                    Cout[(size_t)(mbase + r) * N + n] = acc[i][j][r];
            }
        }
    }
}

// ---------------------------------------------------------------------------
// Flash attention (causal), no-max softmax, work-paired.
// Grid: (16 pairs, 32 bh). Block p does q-tiles {p, 31-p} (64 rows each).
// 4 waves x 16 q-rows. BN=64. Diagonal-only masking.
//
// NEW (R2): double-buffered K/V staging, T3 minimum-2-phase schedule:
//   prologue: STAGE(buf0, it=0); __syncthreads;
//   iter it:  STAGE(buf[cur^1], it+1)   <- issued BEFORE compute
//             compute tile it from buf[cur]
//             __syncthreads (= vmcnt(0)+lgkmcnt(0)+barrier, once per iter)
// Load latency (~300-900 cyc) hides under ~4000 cyc of QK^T/softmax/PV;
// previously the stage was drained serially between two syncthreads.
// setprio(1) wraps MFMA clusters (T5, attn-proven +4-7%).
// LDS: 2*16 + 2*16 + 9 = 73.7 KB -> still 2 blocks/CU (147 KB < 160 KB).
// ---------------------------------------------------------------------------
__global__ __launch_bounds__(256) void attn_kernel(
    const bf16* __restrict__ qt, const bf16* __restrict__ kt,
    const bf16* __restrict__ vt, bf16* __restrict__ o) {
    __shared__ alignas(16) bf16 Ks[2][64 * 128];    // (row, sp): seg = sp ^ (row&15)
    __shared__ alignas(16) bf16 Vts[2][128 * 64];   // (row, sp): seg = sp ^ (row&7)
    __shared__ alignas(16) bf16 Ps[4][16 * 72];     // per-wave P [row][key], stride 72

    const int tid = threadIdx.x;
    const int wave = tid >> 6, lane = tid & 63;
    const int quad = lane >> 4, r16 = lane & 15;
    const int pair = blockIdx.x, bh = blockIdx.y;
    const int b_ = bh >> 4, h = bh & 15;

    // staging: 8 x 16B chunks per thread per tile (4 K + 4 V), XOR-swizzled
    auto stageKV = [&](int buf, int k0) {
#pragma unroll
        for (int j = 0; j < 4; ++j) {
            const int c = tid + j * 256;
            const int row = c >> 4, sp = c & 15, s = sp ^ (row & 15);
            gload_lds16(kt + (((size_t)bh * 2048 + k0 + row) << 7) + s * 8,
                        &Ks[buf][c * 8]);
        }
#pragma unroll
        for (int j = 0; j < 4; ++j) {
            const int c = tid + j * 256;
            const int row = c >> 3, sp = c & 7, s = sp ^ (row & 7);
            gload_lds16(vt + ((size_t)bh * 128 + row) * 2048 + k0 + s * 8,
                        &Vts[buf][c * 8]);
        }
    };

    for (int half = 0; half < 2; ++half) {
        const int t = half == 0 ? pair : 31 - pair;
        const int q0 = t * 64;

        bf16x8 aq[4];
        {
            const bf16* qbase = qt + (((size_t)bh * 2048 + q0 + wave * 16 + r16) << 7);
#pragma unroll
            for (int kc = 0; kc < 4; ++kc)
                aq[kc] = *(const bf16x8*)(qbase + kc * 32 + quad * 8);
        }

        floatx4 oacc[8] = {};
        float lsum[4] = {0.f, 0.f, 0.f, 0.f};

        // prologue: stage tile 0 into buf 0, drain once
        stageKV(0, 0);
        __syncthreads();
        int cur = 0;

        for (int it = 0; it <= t; ++it) {
            // issue next tile's staging early — hides under this tile's compute
            if (it < t) stageKV(cur ^ 1, (it + 1) * 64);

            const bf16* Kc = &Ks[cur][0];
            const bf16* Vc = &Vts[cur][0];

            floatx4 sacc[4] = {};
            __builtin_amdgcn_s_setprio(1);
#pragma unroll
            for (int nt = 0; nt < 4; ++nt) {
                const int row = nt * 16 + r16;
#pragma unroll
                for (int kc = 0; kc < 4; ++kc) {
                    const int sp = (4 * kc + quad) ^ r16;
                    bf16x8 bk = *(const bf16x8*)(Kc + row * 128 + sp * 8);
                    sacc[nt] = MFMA16(aq[kc], bk, sacc[nt]);
                }
            }
            __builtin_amdgcn_s_setprio(0);

            const int qrowC = q0 + wave * 16 + quad * 4;
            const int k0 = it * 64;
            float p[4][4];
            if (it == t) {
#pragma unroll
                for (int nt = 0; nt < 4; ++nt)
#pragma unroll
                    for (int r = 0; r < 4; ++r) {
                        const bool ok = (k0 + nt * 16 + r16) <= (qrowC + r);
                        const float e = ok ? __expf(sacc[nt][r]) : 0.f;
                        p[nt][r] = e;
                        lsum[r] += e;
                    }
            } else {
#pragma unroll
                for (int nt = 0; nt < 4; ++nt)
#pragma unroll
                    for (int r = 0; r < 4; ++r) {
                        const float e = __expf(sacc[nt][r]);
                        p[nt][r] = e;
                        lsum[r] += e;
                    }
            }

#pragma unroll
            for (int nt = 0; nt < 4; ++nt)
#pragma unroll
                for (int r = 0; r < 4; ++r)
                    Ps[wave][(quad * 4 + r) * 72 + nt * 16 + r16] = (bf16)p[nt][r];

            __builtin_amdgcn_s_setprio(1);
#pragma unroll
            for (int kblk = 0; kblk < 2; ++kblk) {
                bf16x8 ap = *(const bf16x8*)(&Ps[wave][r16 * 72 + kblk * 32 + quad * 8]);
#pragma unroll
                for (int nt2 = 0; nt2 < 8; ++nt2) {
                    const int row = nt2 * 16 + r16;
                    const int sp = (4 * kblk + quad) ^ (row & 7);
                    bf16x8 bv = *(const bf16x8*)(Vc + row * 64 + sp * 8);
                    oacc[nt2] = MFMA16(ap, bv, oacc[nt2]);
                }
            }
            __builtin_amdgcn_s_setprio(0);

            // single drain per iter: next tile's loads have had the whole
            // compute phase to land; also releases buf[cur] for re-staging
            __syncthreads();
            cur ^= 1;
        }

#pragma unroll
        for (int r = 0; r < 4; ++r) {
            float s = lsum[r];
#pragma unroll
            for (int off = 1; off < 16; off <<= 1) s += __shfl_xor(s, off);
            lsum[r] = s;
        }

#pragma unroll
        for (int r = 0; r < 4; ++r) {
            const int qq = q0 + wave * 16 + quad * 4 + r;
            const float inv = 1.0f / lsum[r];
            bf16* orow = o + (size_t)(b_ * 2048 + qq) * 2048 + h * 128;
#pragma unroll
            for (int nt2 = 0; nt2 < 8; ++nt2)
                orow[nt2 * 16 + r16] = (bf16)(oacc[nt2][r] * inv);
        }
    }
}

// ---------------------------------------------------------------------------
extern "C" void kernel_launch(void* const* d_in, const int* in_sizes, int n_in,
                              void* d_out, int out_size, void* d_ws, size_t ws_size,
                              hipStream_t stream) {
    const float* x    = (const float*)d_in[0];  // [4096][2048] fp32
    const float* Wqkv = (const float*)d_in[1];  // [2048][6144] fp32
    const float* Wo   = (const float*)d_in[2];  // [2048][2048] fp32
    float* out        = (float*)d_out;          // [4096][2048] fp32

    char* ws = (char*)d_ws;
    bf16* xb    = (bf16*)ws; ws += (size_t)4096 * 2048 * 2;
    bf16* WqkvT = (bf16*)ws; ws += (size_t)6144 * 2048 * 2;
    bf16* WoT   = (bf16*)ws; ws += (size_t)2048 * 2048 * 2;
    bf16* qt    = (bf16*)ws; ws += (size_t)32 * 2048 * 128 * 2;
    bf16* kt    = (bf16*)ws; ws += (size_t)32 * 2048 * 128 * 2;
    bf16* vt    = (bf16*)ws; ws += (size_t)32 * 128 * 2048 * 2;
    bf16* ob    = (bf16*)ws; ws += (size_t)4096 * 2048 * 2;

    downcast_kernel<<<8192, 256, 0, stream>>>(x, xb, (size_t)4096 * 2048);
    transpose_kernel<<<dim3(192, 64), 256, 0, stream>>>(Wqkv, WqkvT, 2048, 6144);
    transpose_kernel<<<dim3(64, 64), 256, 0, stream>>>(Wo, WoT, 2048, 2048);

    gemm_bt_kernel<0><<<dim3(48, 32), 256, 0, stream>>>(
        xb, WqkvT, 4096, 6144, 2048, qt, kt, vt, nullptr);

    attn_kernel<<<dim3(16, 32), 256, 0, stream>>>(qt, kt, vt, ob);

    gemm_bt_kernel<1><<<dim3(16, 32), 256, 0, stream>>>(
        ob, WoT, 4096, 2048, 2048, nullptr, nullptr, nullptr, out);
}